// Round 6
// baseline (129.112 us; speedup 1.0000x reference)
//
#include <hip/hip_runtime.h>

// Involution: B=4, C=256, H=W=56, K=7, GC=16 -> G=16, Cr=64, K2=49
// R6: SINGLE kernel, grid (49 tiles, 8 group-pairs, 4 b) x 256 threads.
//   conv1 recomputed per group-PAIR (8x redundancy; x is L3-resident),
//   chunk loads software-pipelined (vs R4's serial per-chunk loads).
//   Then per g in {2*gq, 2*gq+1}: conv2 GEMM -> lw2 f32; halo f16 -> lxh
//   (overlays conv1 staging buf); fp32-accum apply -> out.
// Removes: k1 dispatch (~13.6us incl. launch/fill-contention) + mid HBM
// round-trip. LDS 31760 B. ws unused.

#define EPS 1e-5f

typedef __fp16 half2t __attribute__((ext_vector_type(2)));
typedef __fp16 half4t __attribute__((ext_vector_type(4)));
typedef __fp16 half8t __attribute__((ext_vector_type(8)));
typedef float floatx4 __attribute__((ext_vector_type(4)));

__device__ inline half8t pack8(float4 u0, float4 u1, float s) {
    half8t a;
    half2t q;
    q = __builtin_amdgcn_cvt_pkrtz(u0.x * s, u0.y * s); a[0] = q[0]; a[1] = q[1];
    q = __builtin_amdgcn_cvt_pkrtz(u0.z * s, u0.w * s); a[2] = q[0]; a[3] = q[1];
    q = __builtin_amdgcn_cvt_pkrtz(u1.x * s, u1.y * s); a[4] = q[0]; a[5] = q[1];
    q = __builtin_amdgcn_cvt_pkrtz(u1.z * s, u1.w * s); a[6] = q[0]; a[7] = q[1];
    return a;
}

// LDS map (bytes):
//   [0, 9216)       bufA [64px][72] f16   - conv1 x-chunk staging (per chunk)
//   [0, 8960)       lxh  [16ch][14][20] f16 halo - overlays bufA AFTER conv1
//   [9216, 18432)   lmid [64px][72] f16   - conv1 output tile (GEMM B-op)
//   [18432, 31760)  lw2  [49][68]   f32   - generated weights (per g, reused)
__global__ __launch_bounds__(256, 4) void k_fused(
    const float* __restrict__ x, const float* __restrict__ w1,
    const float* __restrict__ gamma, const float* __restrict__ beta,
    const float* __restrict__ mean, const float* __restrict__ var,
    const float* __restrict__ cw, const float* __restrict__ cb,
    float* __restrict__ out)
{
    __shared__ __align__(16) unsigned char smem[31760];
    __fp16* bufA = (__fp16*)smem;
    __fp16* lxh  = (__fp16*)smem;
    __fp16* lmid = (__fp16*)(smem + 9216);
    float*  lw2  = (float*)(smem + 18432);

    const int t  = threadIdx.x;
    const int b  = blockIdx.z;
    const int gq = blockIdx.y;
    const int th = blockIdx.x / 7, tw = blockIdx.x % 7;
    const int h0 = th * 8, w0 = tw * 8;
    const int lane = t & 63, wvid = t >> 6;
    const int mrow = lane & 15, quad = lane >> 4;

    // ---------------- conv1: 64px x 64o, K=256 in 4 pipelined chunks -------
    const int orow = wvid * 16 + mrow;
    const float s1 = gamma[orow] * rsqrtf(var[orow] + EPS);

    // A-frags for all 4 chunks (w1 L2-hot), BN scale folded
    half8t A[4][2];
#pragma unroll
    for (int ch = 0; ch < 4; ++ch)
#pragma unroll
        for (int h = 0; h < 2; ++h) {
            const float* src = &w1[orow * 256 + ch * 64 + h * 32 + quad * 8];
            A[ch][h] = pack8(*(const float4*)src, *(const float4*)(src + 4), s1);
        }

    // staging map: c-pair c2 in 0..31, tile-row px8 in 0..7 (8 cols = 2 f4)
    const int c2 = t & 31, px8 = t >> 5;
    const float* xbase = &x[(size_t)(b * 256 + 2 * c2) * 3136 + (h0 + px8) * 56 + w0];

    // prologue: chunk 0 loads
    float4 ca0 = *(const float4*)xbase;
    float4 ca1 = *(const float4*)(xbase + 4);
    float4 cb0 = *(const float4*)(xbase + 3136);
    float4 cb1 = *(const float4*)(xbase + 3140);

    floatx4 acc1[4] = {};
#pragma unroll
    for (int ch = 0; ch < 4; ++ch) {
        // issue next chunk's loads before consuming current
        float4 na0, na1, nb0, nb1;
        if (ch < 3) {
            const float* rn = xbase + (size_t)(ch + 1) * 64 * 3136;
            na0 = *(const float4*)rn;
            na1 = *(const float4*)(rn + 4);
            nb0 = *(const float4*)(rn + 3136);
            nb1 = *(const float4*)(rn + 3140);
        }
        // write current chunk to bufA (f32 -> f16, ch-pair half2)
        float fa[8], fb[8];
        fa[0]=ca0.x; fa[1]=ca0.y; fa[2]=ca0.z; fa[3]=ca0.w;
        fa[4]=ca1.x; fa[5]=ca1.y; fa[6]=ca1.z; fa[7]=ca1.w;
        fb[0]=cb0.x; fb[1]=cb0.y; fb[2]=cb0.z; fb[3]=cb0.w;
        fb[4]=cb1.x; fb[5]=cb1.y; fb[6]=cb1.z; fb[7]=cb1.w;
#pragma unroll
        for (int j = 0; j < 8; ++j) {
            half2t q = __builtin_amdgcn_cvt_pkrtz(fa[j], fb[j]);
            *(half2t*)&bufA[(px8 * 8 + j) * 72 + 2 * c2] = q;
        }
        __syncthreads();
#pragma unroll
        for (int pt = 0; pt < 4; ++pt) {
            half8t bf0 = *(const half8t*)&bufA[(pt * 16 + mrow) * 72 + quad * 8];
            half8t bf1 = *(const half8t*)&bufA[(pt * 16 + mrow) * 72 + quad * 8 + 32];
            acc1[pt] = __builtin_amdgcn_mfma_f32_16x16x32_f16(A[ch][0], bf0, acc1[pt], 0, 0, 0);
            acc1[pt] = __builtin_amdgcn_mfma_f32_16x16x32_f16(A[ch][1], bf1, acc1[pt], 0, 0, 0);
        }
        __syncthreads();
        ca0 = na0; ca1 = na1; cb0 = nb0; cb1 = nb1;
    }

    // conv1 epilogue: bias + relu -> lmid [px][c] f16 (stride 72)
    {
        float bb[4];
#pragma unroll
        for (int i = 0; i < 4; ++i) {
            int o = wvid * 16 + quad * 4 + i;
            float so = gamma[o] * rsqrtf(var[o] + EPS);
            bb[i] = beta[o] - mean[o] * so;
        }
#pragma unroll
        for (int pt = 0; pt < 4; ++pt)
#pragma unroll
            for (int i = 0; i < 4; ++i) {
                float v = fmaxf(acc1[pt][i] + bb[i], 0.f);
                lmid[(pt * 16 + mrow) * 72 + wvid * 16 + quad * 4 + i] = (__fp16)v;
            }
    }
    __syncthreads();   // lmid ready; bufA dead

    // ---- halo prefetch for g0: 16ch x 14rows x 4 f4 ----
    float4 rv4[4];
    int    rslot[4];
#pragma unroll
    for (int i = 0; i < 4; ++i) {
        int s = t + i * 256;
        rslot[i] = s;
        float4 v = make_float4(0.f, 0.f, 0.f, 0.f);
        if (s < 896) {
            int chh = s / 56, r = s % 56;
            int row = r >> 2, q = r & 3;
            int gh = h0 + row - 3;
            int gwb = w0 - 4 + q * 4;
            bool ok = (gh >= 0) & (gh < 56) & (gwb >= 0) & (gwb <= 52);
            int ghc = min(max(gh, 0), 55);
            int gwc = min(max(gwb, 0), 52);
            float4 ld = *(const float4*)&x[(size_t)(b * 256 + (gq * 2) * 16 + chh) * 3136 +
                                           ghc * 56 + gwc];
            if (ok) v = ld;
        }
        rv4[i] = v;
    }

    // ---------------- per-group: GEMM -> halo -> apply ---------------------
#pragma unroll 1
    for (int gi = 0; gi < 2; ++gi) {
        const int g = gq * 2 + gi;

        // conv2 A-frags (cw L2-hot); rows >= 49 are zero
        const int krow = wvid * 16 + mrow;
        half8t a0 = {}, a1 = {};
        if (krow < 49) {
            const float* src = &cw[(size_t)(g * 49 + krow) * 64 + quad * 8];
            a0 = pack8(*(const float4*)src,        *(const float4*)(src + 4),  1.f);
            a1 = pack8(*(const float4*)(src + 32), *(const float4*)(src + 36), 1.f);
        }

        // GEMM: D[49 ko x 64 px] = W_g[49 x 64c] * M[64c x 64px]
        {
            float bias[4];
            int   kor[4];
#pragma unroll
            for (int i = 0; i < 4; ++i) {
                kor[i]  = wvid * 16 + quad * 4 + i;
                bias[i] = (kor[i] < 49) ? cb[g * 49 + kor[i]] : 0.f;
            }
#pragma unroll
            for (int pt = 0; pt < 4; ++pt) {
                half8t b0 = *(const half8t*)&lmid[(pt * 16 + mrow) * 72 + quad * 8];
                half8t b1 = *(const half8t*)&lmid[(pt * 16 + mrow) * 72 + quad * 8 + 32];
                floatx4 acc = {0.f, 0.f, 0.f, 0.f};
                acc = __builtin_amdgcn_mfma_f32_16x16x32_f16(a0, b0, acc, 0, 0, 0);
                acc = __builtin_amdgcn_mfma_f32_16x16x32_f16(a1, b1, acc, 0, 0, 0);
#pragma unroll
                for (int i = 0; i < 4; ++i)
                    if (kor[i] < 49)
                        lw2[kor[i] * 68 + pt * 16 + mrow] = acc[i] + bias[i];
            }
        }
        __syncthreads();   // lw2 ready (and prior apply's reads complete)

        // halo regs -> lxh f16 [ch][row][20] (ch stride 280 halves)
#pragma unroll
        for (int i = 0; i < 4; ++i) {
            int s = rslot[i];
            if (s < 896) {
                int chh = s / 56, r = s % 56;
                int row = r >> 2, q = r & 3;
                half2t p0 = __builtin_amdgcn_cvt_pkrtz(rv4[i].x, rv4[i].y);
                half2t p1 = __builtin_amdgcn_cvt_pkrtz(rv4[i].z, rv4[i].w);
                half4t h; h[0] = p0[0]; h[1] = p0[1]; h[2] = p1[0]; h[3] = p1[1];
                *(half4t*)&lxh[chh * 280 + row * 20 + q * 4] = h;
            }
        }
        // prefetch g1's halo during g0's apply
        if (gi == 0) {
#pragma unroll
            for (int i = 0; i < 4; ++i) {
                int s = rslot[i];
                float4 v = make_float4(0.f, 0.f, 0.f, 0.f);
                if (s < 896) {
                    int chh = s / 56, r = s % 56;
                    int row = r >> 2, q = r & 3;
                    int gh = h0 + row - 3;
                    int gwb = w0 - 4 + q * 4;
                    bool ok = (gh >= 0) & (gh < 56) & (gwb >= 0) & (gwb <= 52);
                    int ghc = min(max(gh, 0), 55);
                    int gwc = min(max(gwb, 0), 52);
                    float4 ld = *(const float4*)&x[(size_t)(b * 256 + (gq * 2 + 1) * 16 + chh) * 3136 +
                                                   ghc * 56 + gwc];
                    if (ok) v = ld;
                }
                rv4[i] = v;
            }
        }
        __syncthreads();   // lxh ready

        // apply: thread = (cc = t>>4 ch, 4 px); f16 x, f32 weights/accum
        {
            const int cc = t >> 4, pxt = t & 15;
            const int sh = pxt >> 1, sw4 = (pxt & 1) * 4;
            float a0f = 0.f, a1f = 0.f, a2f = 0.f, a3f = 0.f;
#pragma unroll
            for (int kh = 0; kh < 7; ++kh) {
                const int rbh = cc * 280 + (sh + kh) * 20 + sw4;
                half4t f0 = *(const half4t*)&lxh[rbh];
                half4t f1 = *(const half4t*)&lxh[rbh + 4];
                half4t f2 = *(const half4t*)&lxh[rbh + 8];
                float xw[12];
#pragma unroll
                for (int j = 0; j < 4; ++j) {
                    xw[j]     = (float)f0[j];
                    xw[j + 4] = (float)f1[j];
                    xw[j + 8] = (float)f2[j];
                }
#pragma unroll
                for (int kw = 0; kw < 7; ++kw) {
                    const float4 wv = *(const float4*)&lw2[(kh * 7 + kw) * 68 + pxt * 4];
                    a0f = fmaf(wv.x, xw[kw + 1], a0f);
                    a1f = fmaf(wv.y, xw[kw + 2], a1f);
                    a2f = fmaf(wv.z, xw[kw + 3], a2f);
                    a3f = fmaf(wv.w, xw[kw + 4], a3f);
                }
            }
            *(float4*)&out[(size_t)(b * 256 + g * 16 + cc) * 3136 +
                           (h0 + sh) * 56 + w0 + sw4] =
                make_float4(a0f, a1f, a2f, a3f);
        }
        __syncthreads();   // lxh/lw2 consumed; next g may overwrite
    }
}

extern "C" void kernel_launch(void* const* d_in, const int* in_sizes, int n_in,
                              void* d_out, int out_size, void* d_ws, size_t ws_size,
                              hipStream_t stream) {
    const float* x     = (const float*)d_in[0];
    const float* w1    = (const float*)d_in[1];
    const float* gamma = (const float*)d_in[2];
    const float* beta  = (const float*)d_in[3];
    const float* mean  = (const float*)d_in[4];
    const float* var   = (const float*)d_in[5];
    const float* cw    = (const float*)d_in[6];
    const float* cb    = (const float*)d_in[7];
    float* out = (float*)d_out;

    (void)d_ws; (void)ws_size;

    k_fused<<<dim3(49, 8, 4), 256, 0, stream>>>(x, w1, gamma, beta, mean, var,
                                                cw, cb, out);
}

// Round 7
// 105.280 us; speedup vs baseline: 1.2264x; 1.2264x over previous
//
#include <hip/hip_runtime.h>

// Involution: B=4, C=256, H=W=56, K=7, GC=16 -> G=16, Cr=64, K2=49
// R7: two-kernel R3 base (best measured) + ONE change: XCD-chunked block
//     swizzle on k2. Grid flattened to 3136 = 8*392; wg=(id%8)*392+id/8 so
//     each XCD owns 8 complete (b,g) panels (same b): halo overlap, mid[b]
//     and cw re-reads become same-XCD L2 hits (unique ~2.1 MB < 4 MB L2).
// ws: mid f16 [4][3136 px][64 c] @0 (1605632 B).

#define EPS 1e-5f

typedef __fp16 half2t __attribute__((ext_vector_type(2)));
typedef __fp16 half8t __attribute__((ext_vector_type(8)));
typedef float floatx4 __attribute__((ext_vector_type(4)));

__device__ inline half8t pack8(float4 u0, float4 u1, float s) {
    half8t a;
    half2t q;
    q = __builtin_amdgcn_cvt_pkrtz(u0.x * s, u0.y * s); a[0] = q[0]; a[1] = q[1];
    q = __builtin_amdgcn_cvt_pkrtz(u0.z * s, u0.w * s); a[2] = q[0]; a[3] = q[1];
    q = __builtin_amdgcn_cvt_pkrtz(u1.x * s, u1.y * s); a[4] = q[0]; a[5] = q[1];
    q = __builtin_amdgcn_cvt_pkrtz(u1.z * s, u1.w * s); a[6] = q[0]; a[7] = q[1];
    return a;
}

// ---------------- Kernel 1: conv1 (1x1, 256->64) + BN + ReLU, MFMA ----------
// grid (98,4): block 64o x 32px. All chunk loads pipelined up front.
__global__ __launch_bounds__(256, 4) void k1_conv1(
    const float* __restrict__ x, const float* __restrict__ w1,
    const float* __restrict__ gamma, const float* __restrict__ beta,
    const float* __restrict__ mean, const float* __restrict__ var,
    __fp16* __restrict__ mid)
{
    __shared__ __align__(16) __fp16 lxB[4 * 32 * 72];  // [chunk][px][72]
    const int t    = threadIdx.x;
    const int b    = blockIdx.y;
    const int p0   = blockIdx.x * 32;
    const int lane = t & 63, wvid = t >> 6;
    const int mrow = lane & 15, quad = lane >> 4;

    // ---- staging loads FIRST: 4 chunks x 2 ch-rows x 4 px, all in flight ----
    const int c2 = t & 31, pxq = t >> 5;             // ch-pair, px-quad
    float4 ra[4], rb[4];
#pragma unroll
    for (int ch = 0; ch < 4; ++ch) {
        const float* r0 = &x[(size_t)(b * 256 + ch * 64 + 2 * c2) * 3136 + p0 + pxq * 4];
        ra[ch] = *(const float4*)r0;
        rb[ch] = *(const float4*)(r0 + 3136);
    }

    // ---- A-fragments meanwhile: BN scale folded, f32 -> f16 (w1 L2-hot) ----
    const int orow = wvid * 16 + mrow;
    const float s = gamma[orow] * rsqrtf(var[orow] + EPS);
    half8t A[4][2];
#pragma unroll
    for (int ch = 0; ch < 4; ++ch)
#pragma unroll
        for (int h = 0; h < 2; ++h) {
            const float* src = &w1[orow * 256 + ch * 64 + h * 32 + quad * 8];
            A[ch][h] = pack8(*(const float4*)src, *(const float4*)(src + 4), s);
        }

    // ---- write all chunks to LDS (cvt to f16), one barrier ----
#pragma unroll
    for (int ch = 0; ch < 4; ++ch) {
        const float* f0 = (const float*)&ra[ch];
        const float* f1 = (const float*)&rb[ch];
#pragma unroll
        for (int j = 0; j < 4; ++j) {
            half2t q = __builtin_amdgcn_cvt_pkrtz(f0[j], f1[j]);
            *(half2t*)&lxB[ch * 2304 + (pxq * 4 + j) * 72 + 2 * c2] = q;
        }
    }
    __syncthreads();

    // ---- MFMA: 16 per wave, no intervening barriers ----
    floatx4 acc[2] = {};
#pragma unroll
    for (int ch = 0; ch < 4; ++ch)
#pragma unroll
        for (int pt = 0; pt < 2; ++pt) {
            half8t bf0 = *(const half8t*)&lxB[ch * 2304 + (pt * 16 + mrow) * 72 + quad * 8];
            half8t bf1 = *(const half8t*)&lxB[ch * 2304 + (pt * 16 + mrow) * 72 + quad * 8 + 32];
            acc[pt] = __builtin_amdgcn_mfma_f32_16x16x32_f16(A[ch][0], bf0, acc[pt], 0, 0, 0);
            acc[pt] = __builtin_amdgcn_mfma_f32_16x16x32_f16(A[ch][1], bf1, acc[pt], 0, 0, 0);
        }
    __syncthreads();

    // ---- epilogue: bias + relu -> f16, transpose via lxB, b128 out ----
    float bb[4];
#pragma unroll
    for (int i = 0; i < 4; ++i) {
        int o = wvid * 16 + quad * 4 + i;
        float so = gamma[o] * rsqrtf(var[o] + EPS);
        bb[i] = beta[o] - mean[o] * so;
    }
#pragma unroll
    for (int pt = 0; pt < 2; ++pt)
#pragma unroll
        for (int i = 0; i < 4; ++i) {
            float v = fmaxf(acc[pt][i] + bb[i], 0.f);
            lxB[(pt * 16 + mrow) * 72 + wvid * 16 + quad * 4 + i] = (__fp16)v;
        }
    __syncthreads();
    {
        int px = t >> 3, o8 = t & 7;                 // 256 slots = 32px x 8
        *(half8t*)&mid[(size_t)(b * 3136 + p0 + px) * 64 + o8 * 8] =
            *(const half8t*)&lxB[px * 72 + o8 * 8];
    }
}

// ---------------- Kernel 2: fused conv2 (f16 MFMA) + unfold/apply (fp32) ----
// grid: 3136 linear blocks, XCD-chunked swizzle (see header comment).
__global__ __launch_bounds__(256, 5) void k23_fused(
    const float* __restrict__ x, const __fp16* __restrict__ mid,
    const float* __restrict__ cw, const float* __restrict__ cb,
    float* __restrict__ out)
{
    // lmid[64px][72] f16 (9216 B) overlaid by lx[16ch][244] f32 (15616 B);
    // lw2[49][68] f32 at 15616 (13328 B). total 28944 B.
    __shared__ __align__(16) unsigned char smem[28944];
    __fp16* lmid = (__fp16*)smem;
    float*  lx   = (float*)smem;                 // ch stride 244, row stride 17
    float*  lw2  = (float*)(smem + 15616);

    const int t  = threadIdx.x;
    // ---- XCD-chunked bijective swizzle: 3136 = 8 XCDs x 392 slots.
    // XCD r owns wg in [r*392, (r+1)*392) = 8 (b,g) panels (same b), tile-fastest.
    const int id   = blockIdx.x;
    const int wg   = (id & 7) * 392 + (id >> 3);
    const int tile = wg % 49;
    const int pg   = wg / 49;                    // pg = b*16 + g
    const int g    = pg & 15;
    const int b    = pg >> 4;
    const int th = tile / 7, tw = tile % 7;
    const int h0 = th * 8, w0 = tw * 8;
    const int lane = t & 63, wvid = t >> 6;
    const int mrow = lane & 15, quad = lane >> 4;

    // ---- halo prefetch FIRST: 16ch x 14rows x 4 f4 (cols w0-4..w0+11) ----
    float4 rv4[4];
    int    rslot[4];
#pragma unroll
    for (int i = 0; i < 4; ++i) {
        int s = t + i * 256;
        rslot[i] = s;
        float4 v = make_float4(0.f, 0.f, 0.f, 0.f);
        if (s < 896) {
            int ch = s / 56, r = s % 56;
            int row = r >> 2, q = r & 3;
            int gh = h0 + row - 3;
            int gwb = w0 - 4 + q * 4;
            bool ok = (gh >= 0) & (gh < 56) & (gwb >= 0) & (gwb <= 52);
            int ghc = min(max(gh, 0), 55);
            int gwc = min(max(gwb, 0), 52);
            float4 ld = *(const float4*)&x[(size_t)(b * 256 + g * 16 + ch) * 3136 +
                                           ghc * 56 + gwc];
            if (ok) v = ld;
        }
        rv4[i] = v;
    }

    // A-fragments: cw f32 -> f16 inline (L2-hot); rows >=49 are zero
    const int krow = wvid * 16 + mrow;
    half8t a0 = {}, a1 = {};
    if (krow < 49) {
        const float* src = &cw[(size_t)(g * 49 + krow) * 64 + quad * 8];
        a0 = pack8(*(const float4*)src,        *(const float4*)(src + 4),  1.f);
        a1 = pack8(*(const float4*)(src + 32), *(const float4*)(src + 36), 1.f);
    }

    // stage lmid [px][c] (stride 72): contiguous-slot b128 copies
#pragma unroll
    for (int i = 0; i < 2; ++i) {
        int s  = t + i * 256;
        int px = s >> 3, c8 = s & 7;
        int pix = (h0 + (px >> 3)) * 56 + w0 + (px & 7);
        *(half8t*)&lmid[px * 72 + c8 * 8] =
            *(const half8t*)&mid[(size_t)(b * 3136 + pix) * 64 + c8 * 8];
    }
    __syncthreads();

    // MFMA GEMM: D[ko][px] = sum_c W[ko][c] * M[c][px]
    {
        float bias[4];
        int   kor[4];
#pragma unroll
        for (int i = 0; i < 4; ++i) {
            kor[i]  = wvid * 16 + quad * 4 + i;
            bias[i] = (kor[i] < 49) ? cb[g * 49 + kor[i]] : 0.f;
        }
#pragma unroll
        for (int pt = 0; pt < 4; ++pt) {
            half8t b0 = *(const half8t*)&lmid[(pt * 16 + mrow) * 72 + quad * 8];
            half8t b1 = *(const half8t*)&lmid[(pt * 16 + mrow) * 72 + quad * 8 + 32];
            floatx4 acc = {0.f, 0.f, 0.f, 0.f};
            acc = __builtin_amdgcn_mfma_f32_16x16x32_f16(a0, b0, acc, 0, 0, 0);
            acc = __builtin_amdgcn_mfma_f32_16x16x32_f16(a1, b1, acc, 0, 0, 0);
#pragma unroll
            for (int i = 0; i < 4; ++i)
                if (kor[i] < 49)
                    lw2[kor[i] * 68 + pt * 16 + mrow] = acc[i] + bias[i];
        }
    }
    __syncthreads();

    // halo f4 regs -> LDS as 4x b32 (ch stride 244, row stride 17, 16 cols)
#pragma unroll
    for (int i = 0; i < 4; ++i) {
        int s = rslot[i];
        if (s < 896) {
            int ch = s / 56, r = s % 56;
            int row = r >> 2, q = r & 3;
            float* dst = &lx[ch * 244 + row * 17 + q * 4];
            dst[0] = rv4[i].x; dst[1] = rv4[i].y;
            dst[2] = rv4[i].z; dst[3] = rv4[i].w;
        }
    }
    __syncthreads();

    // apply: thread = (cc = t>>4, 4 consecutive out px), fp32, b32 lx reads
    const int cc = t >> 4, pxt = t & 15;
    const int sh = pxt >> 1, sw4 = (pxt & 1) * 4;
    float a0f = 0.f, a1f = 0.f, a2f = 0.f, a3f = 0.f;
#pragma unroll
    for (int kh = 0; kh < 7; ++kh) {
        float xr[10];
        const int base = cc * 244 + (sh + kh) * 17 + sw4 + 1;
#pragma unroll
        for (int j = 0; j < 10; ++j) xr[j] = lx[base + j];
#pragma unroll
        for (int kw = 0; kw < 7; ++kw) {
            const float4 wv = *(const float4*)&lw2[(kh * 7 + kw) * 68 + pxt * 4];
            a0f = fmaf(wv.x, xr[kw + 0], a0f);
            a1f = fmaf(wv.y, xr[kw + 1], a1f);
            a2f = fmaf(wv.z, xr[kw + 2], a2f);
            a3f = fmaf(wv.w, xr[kw + 3], a3f);
        }
    }
    *(float4*)&out[(size_t)(b * 256 + g * 16 + cc) * 3136 + (h0 + sh) * 56 + w0 + sw4] =
        make_float4(a0f, a1f, a2f, a3f);
}

extern "C" void kernel_launch(void* const* d_in, const int* in_sizes, int n_in,
                              void* d_out, int out_size, void* d_ws, size_t ws_size,
                              hipStream_t stream) {
    const float* x     = (const float*)d_in[0];
    const float* w1    = (const float*)d_in[1];
    const float* gamma = (const float*)d_in[2];
    const float* beta  = (const float*)d_in[3];
    const float* mean  = (const float*)d_in[4];
    const float* var   = (const float*)d_in[5];
    const float* cw    = (const float*)d_in[6];
    const float* cb    = (const float*)d_in[7];
    float* out = (float*)d_out;

    __fp16* mid = (__fp16*)d_ws;             // 1605632 B

    k1_conv1<<<dim3(98, 4), 256, 0, stream>>>(x, w1, gamma, beta, mean, var, mid);
    k23_fused<<<dim3(3136), 256, 0, stream>>>(x, mid, cw, cb, out);
}